// Round 8
// baseline (62.899 us; speedup 1.0000x reference)
//
#include <hip/hip_runtime.h>

#define NTOT 4096
#define FD 32
#define BATCH 4

typedef __attribute__((ext_vector_type(8))) _Float16 half8;
typedef __attribute__((ext_vector_type(4))) _Float16 half4;
typedef __attribute__((ext_vector_type(2))) _Float16 half2v;
typedef __attribute__((ext_vector_type(4))) float f32x4;

__device__ __forceinline__ float tanh_pos(float t) {
    // tanh(t) for t >= 0:  1 - 2/(1+e^{2t})
    float u = __builtin_amdgcn_exp2f(t * 2.885390081777927f); // e^{2t}
    float r = __builtin_amdgcn_rcpf(u + 1.0f);
    return __builtin_fmaf(-2.0f, r, 1.0f);
}

__device__ __forceinline__ float tanh_poly(float t) {
    // tanh(t) ~= t*(1 - t^2/3 + 2 t^4/15); |err|<3e-6 on [0,0.25], <2e-3 on [0,0.6]
    float t2 = t * t;
    float c = __builtin_fmaf(t2, 0.1333333333f, -0.3333333333f);
    return __builtin_fmaf(t * t2, c, t);
}

__device__ __forceinline__ float eluf(float x) {
    return x > 0.0f ? x : (__builtin_amdgcn_exp2f(x * 1.4426950408889634f) - 1.0f);
}

// X (f32 [B][NT][FD]) -> Kfrag (f16, [B][NT/16 tiles][64 lanes][8]) and
//                        Vfrag (f16, [B][NT/16 tiles][2 fh][64 lanes][4])
// Kfrag[t][l][j]    = X[t*16 + (l&15)][(l>>4)*8 + j]        (B-operand of 16x16x32)
// Vfrag[t][fh][l][j]= X[t*16 + (l>>4)*4 + j][fh*16 + (l&15)] (A-operand of 16x16x16, V^T)
__global__ __launch_bounds__(256) void convert_x(const float* __restrict__ X,
                                                 _Float16* __restrict__ Kfrag,
                                                 _Float16* __restrict__ Vfrag) {
    __shared__ float lds[128 * 33];
    const int tid = threadIdx.x;
    const int blk = blockIdx.x;            // 128 blocks
    const int xcd = blk & 7;
    const int batch = xcd >> 1;
    const int chunk = ((xcd & 1) << 4) | (blk >> 3);  // 0..31
    const int nbase = chunk << 7;                      // 128 rows per chunk

    const float* Xp = X + ((size_t)batch * NTOT + nbase) * FD;
#pragma unroll
    for (int k = 0; k < 16; ++k) {
        int e = tid + k * 256;
        lds[(e >> 5) * 33 + (e & 31)] = Xp[e];
    }
    __syncthreads();

    // Kfrag: 8 tiles * 512 f16
    {
        _Float16* kout = Kfrag + (size_t)batch * NTOT * FD + (size_t)(nbase >> 4) * 512;
        const int tl = tid >> 5;
        const int l0 = (tid & 31) * 2;
#pragma unroll
        for (int s = 0; s < 2; ++s) {
            int l = l0 + s;
            int row = tl * 16 + (l & 15);
            int cb = (l >> 4) * 8;
            half8 v;
#pragma unroll
            for (int j = 0; j < 8; ++j) v[j] = (_Float16)lds[row * 33 + cb + j];
            *(half8*)(kout + (tl * 64 + l) * 8) = v;
        }
    }
    // Vfrag: 8 tiles * 512 f16
    {
        _Float16* vout = Vfrag + (size_t)batch * NTOT * FD + (size_t)(nbase >> 4) * 512;
        const int tl = tid >> 5;
        const int fh = (tid >> 4) & 1;
        const int lb = (tid & 15) * 4;
#pragma unroll
        for (int li = 0; li < 4; ++li) {
            int lane = lb + li;
            int l15 = lane & 15, lg = lane >> 4;
            half4 v;
#pragma unroll
            for (int j = 0; j < 4; ++j)
                v[j] = (_Float16)lds[(tl * 16 + lg * 4 + j) * 33 + fh * 16 + l15];
            *(half4*)(vout + ((tl * 2 + fh) * 64 + lane) * 4) = v;
        }
    }
}

// One GCN layer: out = elu( adj @ V @ W ), adj = tanh(relu(X X^T) + I)
// 16 rows/block, 1024 blocks, 8 waves each owning a 512-col strip (16 iters x 32 cols).
// tanh by cubic poly everywhere; exact tanh fixup only on the 16 diagonal elements.
// LAYER==0: write outHt in Vfrag layout (f16); LAYER==1: write outF (f32 rows).
template <int LAYER>
__global__ __launch_bounds__(512, 8) void gcn_layer_kernel(const _Float16* __restrict__ Kf,
                                                           const _Float16* __restrict__ Vf,
                                                           const float* __restrict__ Wg,
                                                           _Float16* __restrict__ outHt,
                                                           float* __restrict__ outF) {
    __shared__ float lds_part[8 * 32 * 16];  // per-wave partial O^T [wv][f=32][r=16], 16 KB

    const int tid = threadIdx.x;
    const int lane = tid & 63;
    const int wv = tid >> 6;            // 8 waves
    const int blk = blockIdx.x;         // 1024 blocks
    const int xcd = blk & 7;
    const int b = xcd >> 1;             // batch pinned to XCD pair
    const int rowbase = ((((xcd & 1) << 7) | (blk >> 3)) << 4);  // 256 row-tiles/batch
    const int l15 = lane & 15;
    const int lg = lane >> 4;

    const _Float16* KfB = Kf + (size_t)b * NTOT * FD;
    const _Float16* VfB = Vf + (size_t)b * NTOT * FD;

    // Q fragment (tile rowbase/16)
    const half8 q1 = *(const half8*)(KfB + (size_t)(rowbase >> 4) * 512 + lane * 8);

    const int col0 = wv << 9;  // each wave owns 512 columns
    const _Float16* kq = KfB + (size_t)(col0 >> 4) * 512 + lane * 8;
    const _Float16* vq = VfB + (size_t)(col0 >> 4) * 512 + lane * 4;

    f32x4 accA = {0.f, 0.f, 0.f, 0.f};  // fh0, O^T[f 0..15][r]
    f32x4 accB = {0.f, 0.f, 0.f, 0.f};  // fh1, O^T[f 16..31][r]
    const f32x4 zero = {0.f, 0.f, 0.f, 0.f};

    // diagonal bookkeeping: the 16-row diag block lives in 32-col iter diag_it,
    // in the low K-tile if rowbase%32==0 else the high K-tile.
    const int diag_it = ((rowbase & ~31) - col0) >> 5;  // may be out of [0,16)
    const int diag_hi = (rowbase >> 4) & 1;

    // K is 1-deep prefetched; V is loaded at iter top (covered by QK+poly latency).
    half8 k0n = *(const half8*)kq;
    half8 k1n = *(const half8*)(kq + 512);

    for (int it = 0; it < 16; ++it) {
        half4 v00 = *(const half4*)vq;          // tile0, fh0
        half4 v01 = *(const half4*)(vq + 256);  // tile0, fh1
        half4 v10 = *(const half4*)(vq + 512);  // tile1, fh0
        half4 v11 = *(const half4*)(vq + 768);  // tile1, fh1
        vq += 1024;

        half8 k0 = k0n, k1 = k1n;
        if (it < 15) {  // wave-uniform
            kq += 1024;
            k0n = *(const half8*)kq;
            k1n = *(const half8*)(kq + 512);
        }

        // S^T tiles: D[c][r], c = lg*4+e, r = l15
        f32x4 s0 = __builtin_amdgcn_mfma_f32_16x16x32_f16(k0, q1, zero, 0, 0, 0);
        f32x4 s1 = __builtin_amdgcn_mfma_f32_16x16x32_f16(k1, q1, zero, 0, 0, 0);

        float t0[4], t1[4], p0[4], p1[4];
#pragma unroll
        for (int e = 0; e < 4; ++e) {
            t0[e] = fmaxf(s0[e], 0.0f);
            t1[e] = fmaxf(s1[e], 0.0f);
        }
        if (it == diag_it) {  // wave-uniform, 1 of 16 iters
#pragma unroll
            for (int e = 0; e < 4; ++e)
                if (lg * 4 + e == l15) {
                    if (diag_hi) t1[e] += 1.0f; else t0[e] += 1.0f;
                }
        }
#pragma unroll
        for (int e = 0; e < 4; ++e) {
            p0[e] = tanh_poly(t0[e]);
            p1[e] = tanh_poly(t1[e]);
        }
        if (it == diag_it) {  // exact tanh only for the 16 diagonal elements
#pragma unroll
            for (int e = 0; e < 4; ++e)
                if (lg * 4 + e == l15) {
                    if (diag_hi) p1[e] = tanh_pos(t1[e]); else p0[e] = tanh_pos(t0[e]);
                }
        }

        half4 pa = __builtin_shufflevector(
            __builtin_bit_cast(half2v, __builtin_amdgcn_cvt_pkrtz(p0[0], p0[1])),
            __builtin_bit_cast(half2v, __builtin_amdgcn_cvt_pkrtz(p0[2], p0[3])), 0, 1, 2, 3);
        half4 pb = __builtin_shufflevector(
            __builtin_bit_cast(half2v, __builtin_amdgcn_cvt_pkrtz(p1[0], p1[1])),
            __builtin_bit_cast(half2v, __builtin_amdgcn_cvt_pkrtz(p1[2], p1[3])), 0, 1, 2, 3);

        // O^T += V^T * P^T  (S^T D-layout == B-operand layout of 16x16x16)
        accA = __builtin_amdgcn_mfma_f32_16x16x16f16(v00, pa, accA, 0, 0, 0);
        accB = __builtin_amdgcn_mfma_f32_16x16x16f16(v01, pa, accB, 0, 0, 0);
        accA = __builtin_amdgcn_mfma_f32_16x16x16f16(v10, pb, accA, 0, 0, 0);
        accB = __builtin_amdgcn_mfma_f32_16x16x16f16(v11, pb, accB, 0, 0, 0);
    }

    // ---- store per-wave partial O^T [f=32][r=16] ----
#pragma unroll
    for (int e = 0; e < 4; ++e) {
        int f0 = lg * 4 + e;
        lds_part[(wv * 32 + f0) * 16 + l15] = accA[e];
        lds_part[(wv * 32 + 16 + f0) * 16 + l15] = accB[e];
    }
    __syncthreads();

    // ---- reduce 8 wave partials: thread owns flat slot tid (f*16+r) ----
    {
        float ssum = 0.0f;
#pragma unroll
        for (int ww = 0; ww < 8; ++ww) ssum += lds_part[ww * 512 + tid];
        lds_part[tid] = ssum;
    }
    __syncthreads();

    // ---- G = O @ W, elu, write ----
    if (LAYER == 0) {
        // write H1 directly in Vfrag layout: thread -> (fh, lane_v, j)
        const int fh = tid >> 8;            // 0..1
        const int lane_v = (tid >> 2) & 63; // 0..63
        const int j = tid & 3;              // 0..3
        const int g = fh * 16 + (lane_v & 15);
        const int r = (lane_v >> 4) * 4 + j;
        float a = 0.0f;
#pragma unroll
        for (int f = 0; f < FD; ++f)
            a = __builtin_fmaf(lds_part[f * 16 + r], Wg[f * FD + g], a);
        a = eluf(a);
        _Float16* dst = outHt + (size_t)b * NTOT * FD +
                        ((size_t)((rowbase >> 4) * 2 + fh) * 64 + lane_v) * 4 + j;
        *dst = (_Float16)a;
    } else {
        const int g = tid & 31, r = tid >> 5;  // r 0..15
        float a = 0.0f;
#pragma unroll
        for (int f = 0; f < FD; ++f)
            a = __builtin_fmaf(lds_part[f * 16 + r], Wg[f * FD + g], a);
        a = eluf(a);
        outF[((size_t)b * NTOT + rowbase + r) * FD + g] = a;
    }
}

extern "C" void kernel_launch(void* const* d_in, const int* in_sizes, int n_in,
                              void* d_out, int out_size, void* d_ws, size_t ws_size,
                              hipStream_t stream) {
    const float* X = (const float*)d_in[0];  // [B][NT][FD] f32
    const float* W = (const float*)d_in[1];  // [2][FD][FD] f32
    float* out = (float*)d_out;              // [B][NT][FD] f32

    _Float16* Kfrag = (_Float16*)d_ws;                    // 1 MB
    _Float16* VfragX = Kfrag + (size_t)BATCH * NTOT * FD; // 1 MB
    _Float16* H1frag = VfragX + (size_t)BATCH * NTOT * FD;// 1 MB

    convert_x<<<128, 256, 0, stream>>>(X, Kfrag, VfragX);
    gcn_layer_kernel<0><<<1024, 512, 0, stream>>>(Kfrag, VfragX, W, H1frag, nullptr);
    gcn_layer_kernel<1><<<1024, 512, 0, stream>>>(Kfrag, H1frag, W + FD * FD, nullptr, out);
}

// Round 9
// 41.669 us; speedup vs baseline: 1.5095x; 1.5095x over previous
//
#include <hip/hip_runtime.h>

#define NTOT 4096
#define FD 32
#define BATCH 4

typedef __attribute__((ext_vector_type(8))) _Float16 half8;
typedef __attribute__((ext_vector_type(4))) _Float16 half4;
typedef __attribute__((ext_vector_type(2))) _Float16 half2v;
typedef __attribute__((ext_vector_type(4))) float f32x4;

__device__ __forceinline__ float tanh_pos(float t) {
    // tanh(t) for t >= 0:  1 - 2/(1+e^{2t})
    float u = __builtin_amdgcn_exp2f(t * 2.885390081777927f); // e^{2t}
    float r = __builtin_amdgcn_rcpf(u + 1.0f);
    return __builtin_fmaf(-2.0f, r, 1.0f);
}

__device__ __forceinline__ float tanh_poly_f32(float t) {
    float t2 = t * t;
    float c = __builtin_fmaf(t2, 0.1333333333f, -0.3333333333f);
    return __builtin_fmaf(t * t2, c, t);
}

__device__ __forceinline__ float eluf(float x) {
    return x > 0.0f ? x : (__builtin_amdgcn_exp2f(x * 1.4426950408889634f) - 1.0f);
}

// Packed f16 relu + cubic tanh poly: p = max(h,0) * (1 - h^2/3)
// (valid because |s| << 1.73 off-diagonal; diag handled on f32 slow path)
__device__ __forceinline__ half4 pack_relu_poly(f32x4 s) {
    half2v a = __builtin_bit_cast(half2v, __builtin_amdgcn_cvt_pkrtz(s[0], s[1]));
    half2v b = __builtin_bit_cast(half2v, __builtin_amdgcn_cvt_pkrtz(s[2], s[3]));
    const half2v zero = {(_Float16)0.0f, (_Float16)0.0f};
    const half2v mth = {(_Float16)(-0.33333334f), (_Float16)(-0.33333334f)};
    const half2v one = {(_Float16)1.0f, (_Float16)1.0f};
    a = __builtin_elementwise_max(a, zero);
    b = __builtin_elementwise_max(b, zero);
    half2v a2 = a * a, b2 = b * b;
    half2v ca = a2 * mth + one, cb = b2 * mth + one;
    a = a * ca;
    b = b * cb;
    return __builtin_shufflevector(a, b, 0, 1, 2, 3);
}

// X (f32 [B][NT][FD]) -> Kfrag (f16, [B][NT/16 tiles][64 lanes][8]) and
//                        Vfrag (f16, [B][NT/16 tiles][2 fh][64 lanes][4])
// Kfrag[t][l][j]    = X[t*16 + (l&15)][(l>>4)*8 + j]        (B-operand of 16x16x32)
// Vfrag[t][fh][l][j]= X[t*16 + (l>>4)*4 + j][fh*16 + (l&15)] (A-operand of 16x16x16, V^T)
__global__ __launch_bounds__(256) void convert_x(const float* __restrict__ X,
                                                 _Float16* __restrict__ Kfrag,
                                                 _Float16* __restrict__ Vfrag) {
    __shared__ float lds[128 * 33];
    const int tid = threadIdx.x;
    const int blk = blockIdx.x;            // 128 blocks
    const int xcd = blk & 7;
    const int batch = xcd >> 1;
    const int chunk = ((xcd & 1) << 4) | (blk >> 3);  // 0..31
    const int nbase = chunk << 7;                      // 128 rows per chunk

    const float* Xp = X + ((size_t)batch * NTOT + nbase) * FD;
#pragma unroll
    for (int k = 0; k < 16; ++k) {
        int e = tid + k * 256;
        lds[(e >> 5) * 33 + (e & 31)] = Xp[e];
    }
    __syncthreads();

    // Kfrag: 8 tiles * 512 f16
    {
        _Float16* kout = Kfrag + (size_t)batch * NTOT * FD + (size_t)(nbase >> 4) * 512;
        const int tl = tid >> 5;
        const int l0 = (tid & 31) * 2;
#pragma unroll
        for (int s = 0; s < 2; ++s) {
            int l = l0 + s;
            int row = tl * 16 + (l & 15);
            int cb = (l >> 4) * 8;
            half8 v;
#pragma unroll
            for (int j = 0; j < 8; ++j) v[j] = (_Float16)lds[row * 33 + cb + j];
            *(half8*)(kout + (tl * 64 + l) * 8) = v;
        }
    }
    // Vfrag: 8 tiles * 512 f16
    {
        _Float16* vout = Vfrag + (size_t)batch * NTOT * FD + (size_t)(nbase >> 4) * 512;
        const int tl = tid >> 5;
        const int fh = (tid >> 4) & 1;
        const int lb = (tid & 15) * 4;
#pragma unroll
        for (int li = 0; li < 4; ++li) {
            int lane = lb + li;
            int l15 = lane & 15, lg = lane >> 4;
            half4 v;
#pragma unroll
            for (int j = 0; j < 4; ++j)
                v[j] = (_Float16)lds[(tl * 16 + lg * 4 + j) * 33 + fh * 16 + l15];
            *(half4*)(vout + ((tl * 2 + fh) * 64 + lane) * 4) = v;
        }
    }
}

// One GCN layer: out = elu( adj @ V @ W ), adj = tanh(relu(X X^T) + I)
// 32 rows/block, 512 blocks, 8 waves each owning a 512-col strip; 16 fully
// unrolled iters of 32 cols. Off-diag iters: packed-f16 relu+poly (2.5 op/elem).
// Diag iter (1 of 16, wave-uniform): f32 path with exact tanh on diagonal.
// LAYER==0: write outHt in Vfrag layout (f16); LAYER==1: write outF (f32 rows).
template <int LAYER>
__global__ __launch_bounds__(512, 4) void gcn_layer_kernel(const _Float16* __restrict__ Kf,
                                                           const _Float16* __restrict__ Vf,
                                                           const float* __restrict__ Wg,
                                                           _Float16* __restrict__ outHt,
                                                           float* __restrict__ outF) {
    __shared__ float lds_part[8 * 32 * 32];  // per-wave partial O^T [wv][f][r], 32 KB

    const int tid = threadIdx.x;
    const int lane = tid & 63;
    const int wv = tid >> 6;            // 8 waves
    const int blk = blockIdx.x;         // 512 blocks
    const int xcd = blk & 7;
    const int b = xcd >> 1;             // batch pinned to XCD pair
    const int rowbase = ((((xcd & 1) << 6) + (blk >> 3))) << 5;  // 128 row-blocks/batch
    const int l15 = lane & 15;
    const int lg = lane >> 4;

    const _Float16* KfB = Kf + (size_t)b * NTOT * FD;
    const _Float16* VfB = Vf + (size_t)b * NTOT * FD;

    // Q fragments (tiles rowbase/16, +1)
    const half8 q1 = *(const half8*)(KfB + (size_t)(rowbase >> 4) * 512 + lane * 8);
    const half8 q2 = *(const half8*)(KfB + (size_t)((rowbase >> 4) + 1) * 512 + lane * 8);

    const int col0 = wv << 9;  // each wave owns 512 columns
    const _Float16* kq = KfB + (size_t)(col0 >> 4) * 512 + lane * 8;
    const _Float16* vq = VfB + (size_t)(col0 >> 4) * 512 + lane * 4;

    f32x4 accA0 = {0.f, 0.f, 0.f, 0.f}, accA1 = {0.f, 0.f, 0.f, 0.f};
    f32x4 accB0 = {0.f, 0.f, 0.f, 0.f}, accB1 = {0.f, 0.f, 0.f, 0.f};
    const f32x4 zero = {0.f, 0.f, 0.f, 0.f};

    const int diag_it = (rowbase - col0) >> 5;  // iter containing the diagonal (may be OOR)

#pragma unroll
    for (int it = 0; it < 16; ++it) {
        half8 k0 = *(const half8*)(kq + it * 1024);
        half8 k1 = *(const half8*)(kq + it * 1024 + 512);
        half4 v00 = *(const half4*)(vq + it * 1024);        // tile0, fh0
        half4 v01 = *(const half4*)(vq + it * 1024 + 256);  // tile0, fh1
        half4 v10 = *(const half4*)(vq + it * 1024 + 512);  // tile1, fh0
        half4 v11 = *(const half4*)(vq + it * 1024 + 768);  // tile1, fh1

        // S^T tiles: D[c][r], c = lg*4+e, r = l15
        f32x4 s00 = __builtin_amdgcn_mfma_f32_16x16x32_f16(k0, q1, zero, 0, 0, 0);
        f32x4 s01 = __builtin_amdgcn_mfma_f32_16x16x32_f16(k0, q2, zero, 0, 0, 0);
        f32x4 s10 = __builtin_amdgcn_mfma_f32_16x16x32_f16(k1, q1, zero, 0, 0, 0);
        f32x4 s11 = __builtin_amdgcn_mfma_f32_16x16x32_f16(k1, q2, zero, 0, 0, 0);

        half4 p00, p01, p10, p11;
        if (it == diag_it) {  // wave-uniform slow path: diagonal in (k0,q1) & (k1,q2)
            float t00[4], t01[4], t10[4], t11[4];
#pragma unroll
            for (int e = 0; e < 4; ++e) {
                t00[e] = fmaxf(s00[e], 0.0f);
                t01[e] = fmaxf(s01[e], 0.0f);
                t10[e] = fmaxf(s10[e], 0.0f);
                t11[e] = fmaxf(s11[e], 0.0f);
            }
#pragma unroll
            for (int e = 0; e < 4; ++e) {
                bool d = (lg * 4 + e == l15);
                t00[e] = d ? tanh_pos(t00[e] + 1.0f) : tanh_poly_f32(t00[e]);
                t11[e] = d ? tanh_pos(t11[e] + 1.0f) : tanh_poly_f32(t11[e]);
                t01[e] = tanh_poly_f32(t01[e]);
                t10[e] = tanh_poly_f32(t10[e]);
            }
            p00 = __builtin_shufflevector(
                __builtin_bit_cast(half2v, __builtin_amdgcn_cvt_pkrtz(t00[0], t00[1])),
                __builtin_bit_cast(half2v, __builtin_amdgcn_cvt_pkrtz(t00[2], t00[3])), 0, 1, 2, 3);
            p01 = __builtin_shufflevector(
                __builtin_bit_cast(half2v, __builtin_amdgcn_cvt_pkrtz(t01[0], t01[1])),
                __builtin_bit_cast(half2v, __builtin_amdgcn_cvt_pkrtz(t01[2], t01[3])), 0, 1, 2, 3);
            p10 = __builtin_shufflevector(
                __builtin_bit_cast(half2v, __builtin_amdgcn_cvt_pkrtz(t10[0], t10[1])),
                __builtin_bit_cast(half2v, __builtin_amdgcn_cvt_pkrtz(t10[2], t10[3])), 0, 1, 2, 3);
            p11 = __builtin_shufflevector(
                __builtin_bit_cast(half2v, __builtin_amdgcn_cvt_pkrtz(t11[0], t11[1])),
                __builtin_bit_cast(half2v, __builtin_amdgcn_cvt_pkrtz(t11[2], t11[3])), 0, 1, 2, 3);
        } else {  // fast packed-f16 path
            p00 = pack_relu_poly(s00);
            p01 = pack_relu_poly(s01);
            p10 = pack_relu_poly(s10);
            p11 = pack_relu_poly(s11);
        }

        // O^T += V^T * P^T  (S^T D-layout == B-operand layout of 16x16x16)
        accA0 = __builtin_amdgcn_mfma_f32_16x16x16f16(v00, p00, accA0, 0, 0, 0);
        accA1 = __builtin_amdgcn_mfma_f32_16x16x16f16(v00, p01, accA1, 0, 0, 0);
        accB0 = __builtin_amdgcn_mfma_f32_16x16x16f16(v01, p00, accB0, 0, 0, 0);
        accB1 = __builtin_amdgcn_mfma_f32_16x16x16f16(v01, p01, accB1, 0, 0, 0);
        accA0 = __builtin_amdgcn_mfma_f32_16x16x16f16(v10, p10, accA0, 0, 0, 0);
        accA1 = __builtin_amdgcn_mfma_f32_16x16x16f16(v10, p11, accA1, 0, 0, 0);
        accB0 = __builtin_amdgcn_mfma_f32_16x16x16f16(v11, p10, accB0, 0, 0, 0);
        accB1 = __builtin_amdgcn_mfma_f32_16x16x16f16(v11, p11, accB1, 0, 0, 0);
    }

    // ---- store per-wave partial O^T [f=32][r=32] ----
#pragma unroll
    for (int e = 0; e < 4; ++e) {
        int f0 = lg * 4 + e;
        lds_part[(wv * 32 + f0) * 32 + l15] = accA0[e];
        lds_part[(wv * 32 + f0) * 32 + 16 + l15] = accA1[e];
        lds_part[(wv * 32 + 16 + f0) * 32 + l15] = accB0[e];
        lds_part[(wv * 32 + 16 + f0) * 32 + 16 + l15] = accB1[e];
    }
    __syncthreads();

    // ---- reduce 8 wave partials over 1024 (f,r) slots, 2 per thread ----
#pragma unroll
    for (int k = 0; k < 2; ++k) {
        int o = tid + k * 512;
        float ssum = 0.0f;
#pragma unroll
        for (int ww = 0; ww < 8; ++ww) ssum += lds_part[ww * 1024 + o];
        lds_part[o] = ssum;
    }
    __syncthreads();

    // ---- G = O @ W, elu, write ----
    if (LAYER == 0) {
        // write H1 directly in Vfrag layout (2 f16 per thread)
        const int jp = tid & 1;
        const int vlane = (tid >> 1) & 63;
        const int fh = (tid >> 7) & 1;
        const int tl = tid >> 8;  // 0..1
        const int vl15 = vlane & 15, vlg = vlane >> 4;
        const int g = fh * 16 + vl15;
        const int r0 = tl * 16 + vlg * 4 + jp * 2;
        float a0 = 0.0f, a1 = 0.0f;
#pragma unroll
        for (int f = 0; f < FD; ++f) {
            float w = Wg[f * FD + g];
            a0 = __builtin_fmaf(lds_part[f * 32 + r0], w, a0);
            a1 = __builtin_fmaf(lds_part[f * 32 + r0 + 1], w, a1);
        }
        a0 = eluf(a0);
        a1 = eluf(a1);
        unsigned pk = __builtin_bit_cast(unsigned, __builtin_amdgcn_cvt_pkrtz(a0, a1));
        _Float16* dst = outHt + (size_t)b * NTOT * FD +
                        ((size_t)(((rowbase >> 4) + tl) * 2 + fh) * 64 + vlane) * 4 + jp * 2;
        *(unsigned*)dst = pk;
    } else {
        const int g = tid & 31, r0 = tid >> 5;  // rows r0, r0+16
        float a0 = 0.0f, a1 = 0.0f;
#pragma unroll
        for (int f = 0; f < FD; ++f) {
            float w = Wg[f * FD + g];
            a0 = __builtin_fmaf(lds_part[f * 32 + r0], w, a0);
            a1 = __builtin_fmaf(lds_part[f * 32 + r0 + 16], w, a1);
        }
        a0 = eluf(a0);
        a1 = eluf(a1);
        float* dst = outF + ((size_t)b * NTOT + rowbase) * FD + g;
        dst[(size_t)r0 * FD] = a0;
        dst[(size_t)(r0 + 16) * FD] = a1;
    }
}

extern "C" void kernel_launch(void* const* d_in, const int* in_sizes, int n_in,
                              void* d_out, int out_size, void* d_ws, size_t ws_size,
                              hipStream_t stream) {
    const float* X = (const float*)d_in[0];  // [B][NT][FD] f32
    const float* W = (const float*)d_in[1];  // [2][FD][FD] f32
    float* out = (float*)d_out;              // [B][NT][FD] f32

    _Float16* Kfrag = (_Float16*)d_ws;                    // 1 MB
    _Float16* VfragX = Kfrag + (size_t)BATCH * NTOT * FD; // 1 MB
    _Float16* H1frag = VfragX + (size_t)BATCH * NTOT * FD;// 1 MB

    convert_x<<<128, 256, 0, stream>>>(X, Kfrag, VfragX);
    gcn_layer_kernel<0><<<512, 512, 0, stream>>>(Kfrag, VfragX, W, H1frag, nullptr);
    gcn_layer_kernel<1><<<512, 512, 0, stream>>>(Kfrag, H1frag, W + FD * FD, nullptr, out);
}

// Round 10
// 37.345 us; speedup vs baseline: 1.6843x; 1.1158x over previous
//
#include <hip/hip_runtime.h>

#define NTOT 4096
#define FD 32
#define BATCH 4

typedef __attribute__((ext_vector_type(8))) _Float16 half8;
typedef __attribute__((ext_vector_type(4))) _Float16 half4;
typedef __attribute__((ext_vector_type(2))) _Float16 half2v;
typedef __attribute__((ext_vector_type(4))) float f32x4;

__device__ __forceinline__ float tanh_pos(float t) {
    float u = __builtin_amdgcn_exp2f(t * 2.885390081777927f); // e^{2t}
    float r = __builtin_amdgcn_rcpf(u + 1.0f);
    return __builtin_fmaf(-2.0f, r, 1.0f);
}

__device__ __forceinline__ float tanh_poly_f32(float t) {
    float t2 = t * t;
    float c = __builtin_fmaf(t2, 0.1333333333f, -0.3333333333f);
    return __builtin_fmaf(t * t2, c, t);
}

__device__ __forceinline__ float eluf(float x) {
    return x > 0.0f ? x : (__builtin_amdgcn_exp2f(x * 1.4426950408889634f) - 1.0f);
}

// Packed f16 relu + cubic tanh poly: p = max(h,0) * (1 - h^2/3)
__device__ __forceinline__ half4 pack_relu_poly(f32x4 s) {
    half2v a = __builtin_bit_cast(half2v, __builtin_amdgcn_cvt_pkrtz(s[0], s[1]));
    half2v b = __builtin_bit_cast(half2v, __builtin_amdgcn_cvt_pkrtz(s[2], s[3]));
    const half2v zero = {(_Float16)0.0f, (_Float16)0.0f};
    const half2v mth = {(_Float16)(-0.33333334f), (_Float16)(-0.33333334f)};
    const half2v one = {(_Float16)1.0f, (_Float16)1.0f};
    a = __builtin_elementwise_max(a, zero);
    b = __builtin_elementwise_max(b, zero);
    half2v a2 = a * a, b2 = b * b;
    half2v ca = a2 * mth + one, cb = b2 * mth + one;
    a = a * ca;
    b = b * cb;
    return __builtin_shufflevector(a, b, 0, 1, 2, 3);
}

// f32 slow path for the diagonal 16x16 tile: exact tanh(t+1) at c==r
__device__ __forceinline__ half4 diag_transform(f32x4 s, int l15, int lg) {
    float t[4];
#pragma unroll
    for (int e = 0; e < 4; ++e) t[e] = fmaxf(s[e], 0.0f);
#pragma unroll
    for (int e = 0; e < 4; ++e) {
        bool d = (lg * 4 + e == l15);
        t[e] = d ? tanh_pos(t[e] + 1.0f) : tanh_poly_f32(t[e]);
    }
    return __builtin_shufflevector(
        __builtin_bit_cast(half2v, __builtin_amdgcn_cvt_pkrtz(t[0], t[1])),
        __builtin_bit_cast(half2v, __builtin_amdgcn_cvt_pkrtz(t[2], t[3])), 0, 1, 2, 3);
}

// X (f32 [B][NT][FD]) -> Kfrag (f16, [B][NT/16 tiles][64 lanes][8]) and
//                        Vfrag (f16, [B][NT/16 tiles][2 fh][64 lanes][4])
__global__ __launch_bounds__(256) void convert_x(const float* __restrict__ X,
                                                 _Float16* __restrict__ Kfrag,
                                                 _Float16* __restrict__ Vfrag) {
    __shared__ float lds[128 * 33];
    const int tid = threadIdx.x;
    const int blk = blockIdx.x;            // 128 blocks
    const int xcd = blk & 7;
    const int batch = xcd >> 1;
    const int chunk = ((xcd & 1) << 4) | (blk >> 3);  // 0..31
    const int nbase = chunk << 7;                      // 128 rows per chunk

    const float* Xp = X + ((size_t)batch * NTOT + nbase) * FD;
#pragma unroll
    for (int k = 0; k < 16; ++k) {
        int e = tid + k * 256;
        lds[(e >> 5) * 33 + (e & 31)] = Xp[e];
    }
    __syncthreads();

    {
        _Float16* kout = Kfrag + (size_t)batch * NTOT * FD + (size_t)(nbase >> 4) * 512;
        const int tl = tid >> 5;
        const int l0 = (tid & 31) * 2;
#pragma unroll
        for (int s = 0; s < 2; ++s) {
            int l = l0 + s;
            int row = tl * 16 + (l & 15);
            int cb = (l >> 4) * 8;
            half8 v;
#pragma unroll
            for (int j = 0; j < 8; ++j) v[j] = (_Float16)lds[row * 33 + cb + j];
            *(half8*)(kout + (tl * 64 + l) * 8) = v;
        }
    }
    {
        _Float16* vout = Vfrag + (size_t)batch * NTOT * FD + (size_t)(nbase >> 4) * 512;
        const int tl = tid >> 5;
        const int fh = (tid >> 4) & 1;
        const int lb = (tid & 15) * 4;
#pragma unroll
        for (int li = 0; li < 4; ++li) {
            int lane = lb + li;
            int l15 = lane & 15, lg = lane >> 4;
            half4 v;
#pragma unroll
            for (int j = 0; j < 4; ++j)
                v[j] = (_Float16)lds[(tl * 16 + lg * 4 + j) * 33 + fh * 16 + l15];
            *(half4*)(vout + ((tl * 2 + fh) * 64 + lane) * 4) = v;
        }
    }
}

// One GCN layer: out = elu( adj @ V @ W ), adj = tanh(relu(X X^T) + I)
// 64 rows/block, 256 blocks (1/CU), 16 waves (1024 thr) each owning a 256-col
// strip; 8 fully-unrolled iters of 32 cols. Per iter: 8 QK MFMA + 8 packed
// transforms + 16 PV MFMA. Partial O^T stored as f16 [16 wv][64 r][32 f] (64 KB).
// LAYER==0: write outHt in Vfrag layout (f16); LAYER==1: write outF (f32 rows).
template <int LAYER>
__global__ __launch_bounds__(1024, 4) void gcn_layer_kernel(const _Float16* __restrict__ Kf,
                                                            const _Float16* __restrict__ Vf,
                                                            const float* __restrict__ Wg,
                                                            _Float16* __restrict__ outHt,
                                                            float* __restrict__ outF) {
    __shared__ _Float16 lds_part[16 * 64 * 32];  // [wv][r][f] f16, 64 KB

    const int tid = threadIdx.x;
    const int lane = tid & 63;
    const int wv = tid >> 6;            // 16 waves
    const int blk = blockIdx.x;         // 256 blocks
    const int xcd = blk & 7;
    const int b = xcd >> 1;             // batch pinned to XCD pair
    const int rowidx = ((xcd & 1) << 5) | (blk >> 3);  // 0..63
    const int rowbase = rowidx << 6;                   // 64 rows per block
    const int l15 = lane & 15;
    const int lg = lane >> 4;

    const _Float16* KfB = Kf + (size_t)b * NTOT * FD;
    const _Float16* VfB = Vf + (size_t)b * NTOT * FD;

    // Q fragments: 4 row-tiles
    half8 q[4];
#pragma unroll
    for (int qt = 0; qt < 4; ++qt)
        q[qt] = *(const half8*)(KfB + (size_t)((rowbase >> 4) + qt) * 512 + lane * 8);

    const int col0 = wv << 8;  // each wave owns 256 columns
    const _Float16* kq = KfB + (size_t)(col0 >> 4) * 512 + lane * 8;
    const _Float16* vq = VfB + (size_t)(col0 >> 4) * 512 + lane * 4;

    f32x4 accA[4], accB[4];
#pragma unroll
    for (int qt = 0; qt < 4; ++qt) {
        accA[qt] = (f32x4){0.f, 0.f, 0.f, 0.f};
        accB[qt] = (f32x4){0.f, 0.f, 0.f, 0.f};
    }
    const f32x4 zero = {0.f, 0.f, 0.f, 0.f};

    // diagonal iterations: diagA covers cols rowbase..+31 (pairs k0/q0, k1/q1),
    // diagA+1 covers cols rowbase+32..+63 (pairs k0/q2, k1/q3).
    const int diagA = (rowbase - col0) >> 5;  // may be out of [0,8)

#pragma unroll
    for (int it = 0; it < 8; ++it) {
        const int base = it * 1024;
        half8 k0 = *(const half8*)(kq + base);
        half8 k1 = *(const half8*)(kq + base + 512);
        half4 v00 = *(const half4*)(vq + base);        // tile0, fh0
        half4 v01 = *(const half4*)(vq + base + 256);  // tile0, fh1
        half4 v10 = *(const half4*)(vq + base + 512);  // tile1, fh0
        half4 v11 = *(const half4*)(vq + base + 768);  // tile1, fh1

        f32x4 s0[4], s1[4];
#pragma unroll
        for (int qt = 0; qt < 4; ++qt) {
            s0[qt] = __builtin_amdgcn_mfma_f32_16x16x32_f16(k0, q[qt], zero, 0, 0, 0);
            s1[qt] = __builtin_amdgcn_mfma_f32_16x16x32_f16(k1, q[qt], zero, 0, 0, 0);
        }

        half4 p0[4], p1[4];
#pragma unroll
        for (int qt = 0; qt < 4; ++qt) {
            p0[qt] = pack_relu_poly(s0[qt]);
            p1[qt] = pack_relu_poly(s1[qt]);
        }
        if (it == diagA) {        // wave-uniform
            p0[0] = diag_transform(s0[0], l15, lg);
            p1[1] = diag_transform(s1[1], l15, lg);
        }
        if (it == diagA + 1) {    // wave-uniform
            p0[2] = diag_transform(s0[2], l15, lg);
            p1[3] = diag_transform(s1[3], l15, lg);
        }

        // O^T += V^T * P^T  (S^T D-layout == B-operand layout of 16x16x16)
#pragma unroll
        for (int qt = 0; qt < 4; ++qt) {
            accA[qt] = __builtin_amdgcn_mfma_f32_16x16x16f16(v00, p0[qt], accA[qt], 0, 0, 0);
            accB[qt] = __builtin_amdgcn_mfma_f32_16x16x16f16(v01, p0[qt], accB[qt], 0, 0, 0);
            accA[qt] = __builtin_amdgcn_mfma_f32_16x16x16f16(v10, p1[qt], accA[qt], 0, 0, 0);
            accB[qt] = __builtin_amdgcn_mfma_f32_16x16x16f16(v11, p1[qt], accB[qt], 0, 0, 0);
        }
    }

    // ---- store per-wave partial O^T as f16, layout [wv][r=64][f=32] ----
    // accA[qt][e] = O^T[f=lg*4+e][r=qt*16+l15]; pack 4 f along f -> one 8B store
#pragma unroll
    for (int qt = 0; qt < 4; ++qt) {
        half4 pa = __builtin_shufflevector(
            __builtin_bit_cast(half2v, __builtin_amdgcn_cvt_pkrtz(accA[qt][0], accA[qt][1])),
            __builtin_bit_cast(half2v, __builtin_amdgcn_cvt_pkrtz(accA[qt][2], accA[qt][3])), 0, 1, 2, 3);
        half4 pb = __builtin_shufflevector(
            __builtin_bit_cast(half2v, __builtin_amdgcn_cvt_pkrtz(accB[qt][0], accB[qt][1])),
            __builtin_bit_cast(half2v, __builtin_amdgcn_cvt_pkrtz(accB[qt][2], accB[qt][3])), 0, 1, 2, 3);
        int r = qt * 16 + l15;
        *(half4*)(lds_part + (wv * 64 + r) * 32 + lg * 4) = pa;
        *(half4*)(lds_part + (wv * 64 + r) * 32 + 16 + lg * 4) = pb;
    }
    __syncthreads();

    // ---- reduce 16 wave partials; each thread owns slots tid and tid+1024 ----
    float red0 = 0.0f, red1 = 0.0f;
#pragma unroll
    for (int ww = 0; ww < 16; ++ww) {
        red0 += (float)lds_part[ww * 2048 + tid];
        red1 += (float)lds_part[ww * 2048 + tid + 1024];
    }
    __syncthreads();
    float* ldsf = (float*)lds_part;  // reuse first 8 KB as f32 [r=64][f=32]
    ldsf[tid] = red0;
    ldsf[tid + 1024] = red1;
    __syncthreads();

    // ---- G = O @ W, elu, write ----
    if (LAYER == 0) {
        // write H1 in Vfrag layout, 2 f16 per thread
        const int jp = tid & 1;
        const int lane_v = (tid >> 1) & 63;
        const int fh = (tid >> 7) & 1;
        const int tl = tid >> 8;  // 0..3
        const int g = fh * 16 + (lane_v & 15);
        const int r0 = tl * 16 + ((lane_v >> 4) << 2) + jp * 2;
        float a0 = 0.0f, a1 = 0.0f;
#pragma unroll
        for (int f = 0; f < FD; ++f) {
            float w = Wg[f * FD + g];
            a0 = __builtin_fmaf(ldsf[r0 * FD + f], w, a0);
            a1 = __builtin_fmaf(ldsf[(r0 + 1) * FD + f], w, a1);
        }
        a0 = eluf(a0);
        a1 = eluf(a1);
        unsigned pk = __builtin_bit_cast(unsigned, __builtin_amdgcn_cvt_pkrtz(a0, a1));
        _Float16* dst = outHt + (size_t)b * NTOT * FD +
                        ((size_t)(((rowbase >> 4) + tl) * 2 + fh) * 64 + lane_v) * 4 + jp * 2;
        *(unsigned*)dst = pk;
    } else {
        const int g = tid & 31, r0 = tid >> 5;  // rows r0, r0+32
        float a0 = 0.0f, a1 = 0.0f;
#pragma unroll
        for (int f = 0; f < FD; ++f) {
            float w = Wg[f * FD + g];
            a0 = __builtin_fmaf(ldsf[r0 * FD + f], w, a0);
            a1 = __builtin_fmaf(ldsf[(r0 + 32) * FD + f], w, a1);
        }
        a0 = eluf(a0);
        a1 = eluf(a1);
        float* dst = outF + ((size_t)b * NTOT + rowbase) * FD + g;
        dst[(size_t)r0 * FD] = a0;
        dst[(size_t)(r0 + 32) * FD] = a1;
    }
}

extern "C" void kernel_launch(void* const* d_in, const int* in_sizes, int n_in,
                              void* d_out, int out_size, void* d_ws, size_t ws_size,
                              hipStream_t stream) {
    const float* X = (const float*)d_in[0];  // [B][NT][FD] f32
    const float* W = (const float*)d_in[1];  // [2][FD][FD] f32
    float* out = (float*)d_out;              // [B][NT][FD] f32

    _Float16* Kfrag = (_Float16*)d_ws;                    // 1 MB
    _Float16* VfragX = Kfrag + (size_t)BATCH * NTOT * FD; // 1 MB
    _Float16* H1frag = VfragX + (size_t)BATCH * NTOT * FD;// 1 MB

    convert_x<<<128, 256, 0, stream>>>(X, Kfrag, VfragX);
    gcn_layer_kernel<0><<<256, 1024, 0, stream>>>(Kfrag, VfragX, W, H1frag, nullptr);
    gcn_layer_kernel<1><<<256, 1024, 0, stream>>>(Kfrag, H1frag, W + FD * FD, nullptr, out);
}